// Round 11
// baseline (1591.134 us; speedup 1.0000x reference)
//
#include <hip/hip_runtime.h>
#include <stdint.h>
#include <stddef.h>

#define BATCH 128
#define NFRAMES 256
#define EMBED 768
#define RES 2048
#define NCLS 1000
#define NWG 256

typedef __attribute__((ext_vector_type(8))) short bf16x8;
typedef __attribute__((ext_vector_type(4))) float f32x4;
typedef unsigned short u16;

__device__ inline u16 f2bf(float f) {
    union { float f; unsigned u; } v; v.f = f;
    unsigned r = v.u + 0x7FFFu + ((v.u >> 16) & 1u);
    return (u16)(r >> 16);
}
__device__ inline float bf2f(u16 h) {
    union { unsigned u; float f; } v; v.u = ((unsigned)h) << 16;
    return v.f;
}
// tanh(x) = 1 - 2/(e^{2x}+1), via HW exp2 + rcp (4 VALU ops, saturates correctly)
__device__ inline float tanh_fast(float x) {
    float z = __builtin_amdgcn_exp2f(x * 2.885390081777927f);  // e^{2x}
    return 1.f - 2.f * __builtin_amdgcn_rcpf(z + 1.f);
}

// ---------------- fp32 -> bf16 convert, vectorized x4 ----------------
__global__ __launch_bounds__(256) void cvt_kernel(const float* __restrict__ in,
                                                  u16* __restrict__ out, int n4) {
    int i = blockIdx.x * blockDim.x + threadIdx.x;
    int stride = gridDim.x * blockDim.x;
    for (; i < n4; i += stride) {
        float4 v = ((const float4*)in)[i];
        ushort4 o;
        o.x = f2bf(v.x); o.y = f2bf(v.y); o.z = f2bf(v.z); o.w = f2bf(v.w);
        ((ushort4*)out)[i] = o;
    }
}

// ---------------- projection: u[t,b,r] = sum_e x[b,t,e] * W_in[r,e] ----------------
__global__ __launch_bounds__(256) void proj_kernel(const u16* __restrict__ xb,
                                                   const u16* __restrict__ win,
                                                   u16* __restrict__ u) {
    int lane = threadIdx.x & 63;
    int w = threadIdx.x >> 6;
    int wm = w >> 1, wn = w & 1;
    int m0 = blockIdx.x * 128 + wm * 64;
    int n0 = blockIdx.y * 128 + wn * 64;
    int lr = lane & 15;
    int lk = (lane >> 4) * 8;

    f32x4 acc[4][4];
#pragma unroll
    for (int i = 0; i < 4; i++)
#pragma unroll
        for (int j = 0; j < 4; j++) acc[i][j] = (f32x4)0.f;

    for (int kk = 0; kk < EMBED; kk += 32) {
        bf16x8 a[4], b[4];
#pragma unroll
        for (int i = 0; i < 4; i++)
            a[i] = *(const bf16x8*)(xb + (size_t)(m0 + i * 16 + lr) * EMBED + kk + lk);
#pragma unroll
        for (int j = 0; j < 4; j++)
            b[j] = *(const bf16x8*)(win + (size_t)(n0 + j * 16 + lr) * EMBED + kk + lk);
#pragma unroll
        for (int i = 0; i < 4; i++)
#pragma unroll
            for (int j = 0; j < 4; j++)
                acc[i][j] = __builtin_amdgcn_mfma_f32_16x16x32_bf16(a[i], b[j], acc[i][j], 0, 0, 0);
    }

    int rowbase = (lane >> 4) * 4;
#pragma unroll
    for (int i = 0; i < 4; i++) {
#pragma unroll
        for (int j = 0; j < 4; j++) {
#pragma unroll
            for (int q = 0; q < 4; q++) {
                int m = m0 + i * 16 + rowbase + q;   // row index = b*NFRAMES + t
                int n = n0 + j * 16 + lr;            // reservoir index
                int bb = m >> 8, tt = m & 255;
                u[((size_t)tt * BATCH + bb) * RES + n] = f2bf(acc[i][j][q]);
            }
        }
    }
}

// ---------------- persistent recurrence, per-wave producer polling ----------------
// Batch rows independent -> 8 row-groups of 32 WGs. WG tile 16 rows x 64 cols.
// Wave w consumes K [w*256, w*256+256) = slices of producers c' = 4w..4w+3 ONLY.
// Each wave polls its own 4 flags (one uniform dwordx4) and starts its loads/MFMA
// immediately -> no WG-wide convoy, A-load latency overlaps producer tails.
// Store safety: WG stores step t only after all 8 waves polled (all 32 producers
// stamped t) => everyone finished reading the ping-pong buffer being overwritten.
// Stamps monotone (= completed step + 1); no reset, no deadlock.
__global__ __launch_bounds__(512, 1) void recur_kernel(const u16* __restrict__ res,
                                                       const u16* __restrict__ u,
                                                       u16* __restrict__ s0,
                                                       u16* __restrict__ s1,
                                                       unsigned* __restrict__ flags) {
    __shared__ float part[8][16][66];
    const int lane = threadIdx.x & 63;
    const int w = threadIdx.x >> 6;          // K-slice 0..7
    const int rowgrp = (int)(blockIdx.x & 7);
    const int colblk = (int)(blockIdx.x >> 3);
    const int m0 = rowgrp * 16;
    const int n0 = colblk * 64;
    const int lr = lane & 15;
    const int lk = (lane >> 4) * 8;
    const int rb = (lane >> 4) * 4;
    const int kbase = w * 256;
    unsigned* myflag = flags + rowgrp * 32 + colblk;
    const unsigned* wflags = flags + rowgrp * 32 + w * 4;   // this wave's 4 producers
    const bool ownInRange = ((colblk >> 2) == w);
    const int ownIdx = colblk & 3;

    // persistent reservoir B-fragments: 4 col-frags x 8 K-subs = 128 VGPR/lane
    bf16x8 bfr[4][8];
#pragma unroll
    for (int jf = 0; jf < 4; jf++)
#pragma unroll
        for (int kk = 0; kk < 8; kk++)
            bfr[jf][kk] = *(const bf16x8*)(res + (size_t)(n0 + jf * 16 + lr) * RES + kbase + kk * 32 + lk);

    // epilogue mapping: thread -> (row 0..15, col pair)
    const int er = threadIdx.x >> 5;          // 0..15
    const int ec = (threadIdx.x & 31) * 2;    // 0..62
    const size_t gidx = (size_t)(m0 + er) * RES + n0 + ec;

    for (int t = 0; t < NFRAMES; t++) {
        const u16* sin = (t & 1) ? s1 : s0;
        u16* sout = (t & 1) ? s0 : s1;
        const u16* abase = sin + (size_t)(m0 + lr) * RES + kbase + lk;

        // u prefetch (immutable input, cached; issued before the poll)
        unsigned uv = *(const unsigned*)(u + (size_t)t * BATCH * RES + gidx);

        // per-wave poll: wait until this wave's 4 producers completed step t-1
        if (t > 0) {
            unsigned stamp = (unsigned)t;
            do {
                uint4 f;
                asm volatile("global_load_dwordx4 %0, %1, off sc0 sc1\n\ts_waitcnt vmcnt(0)"
                             : "=v"(f) : "v"(wflags) : "memory");
                if (ownInRange) ((unsigned*)&f)[ownIdx] = 0xFFFFFFFFu;  // own slice: known done
                unsigned mn = min(min(f.x, f.y), min(f.z, f.w));
                if (mn >= stamp) break;
                __builtin_amdgcn_s_sleep(1);
            } while (1);
        }

        // 8 A-loads (16 rows x 256 K slice, uncached wide), pipelined MFMA
        bf16x8 a[8];
#pragma unroll
        for (int kk = 0; kk < 8; kk++)
            asm volatile("global_load_dwordx4 %0, %1, off sc0 sc1"
                         : "=v"(a[kk]) : "v"(abase + kk * 32));

        f32x4 acc[4];
#pragma unroll
        for (int jf = 0; jf < 4; jf++) acc[jf] = (f32x4)0.f;

        asm volatile("s_waitcnt vmcnt(4)" ::: "memory");
        __builtin_amdgcn_sched_barrier(0);
#pragma unroll
        for (int kk = 0; kk < 4; kk++)
#pragma unroll
            for (int jf = 0; jf < 4; jf++)
                acc[jf] = __builtin_amdgcn_mfma_f32_16x16x32_bf16(a[kk], bfr[jf][kk], acc[jf], 0, 0, 0);
        asm volatile("s_waitcnt vmcnt(0)" ::: "memory");
        __builtin_amdgcn_sched_barrier(0);
#pragma unroll
        for (int kk = 4; kk < 8; kk++)
#pragma unroll
            for (int jf = 0; jf < 4; jf++)
                acc[jf] = __builtin_amdgcn_mfma_f32_16x16x32_bf16(a[kk], bfr[jf][kk], acc[jf], 0, 0, 0);

        // K-partials -> LDS
#pragma unroll
        for (int jf = 0; jf < 4; jf++)
#pragma unroll
            for (int q = 0; q < 4; q++)
                part[w][rb + q][jf * 16 + lr] = acc[jf][q];
        __syncthreads();

        // reduce 8 K-partials + u add + fast tanh + packed write-through store
        float sx = 0.f, sy = 0.f;
#pragma unroll
        for (int ww = 0; ww < 8; ww++) {
            float2 v = *(const float2*)&part[ww][er][ec];
            sx += v.x; sy += v.y;
        }
        float v0 = tanh_fast(sx + bf2f((u16)(uv & 0xFFFF)));
        float v1 = tanh_fast(sy + bf2f((u16)(uv >> 16)));
        unsigned pk = (unsigned)f2bf(v0) | ((unsigned)f2bf(v1) << 16);
        asm volatile("global_store_dword %0, %1, off sc0 sc1"
                     :: "v"(sout + gidx), "v"(pk) : "memory");

        // drain own store (write-through -> visible at IF), join waves, stamp.
        asm volatile("s_waitcnt vmcnt(0)" ::: "memory");
        __syncthreads();   // all 512 stores drained; also protects part[] reuse
        if (t != NFRAMES - 1) {
            if (threadIdx.x == 0) {
                unsigned stamp = (unsigned)(t + 1);
                asm volatile("global_store_dword %0, %1, off sc0 sc1"
                             :: "v"(myflag), "v"(stamp) : "memory");
            }
        }
    }
}

// ---------------- head: logits[b,c] = sum_r s[b,r]*W_out[c,r] + bias[c] ----------------
__global__ __launch_bounds__(512) void head_kernel(const u16* __restrict__ sin,
                                                   const u16* __restrict__ wout,
                                                   const float* __restrict__ bias,
                                                   float* __restrict__ out) {
    __shared__ float part[8][32][33];
    int lane = threadIdx.x & 63;
    int w = threadIdx.x >> 6;
    int m0 = blockIdx.x * 32;
    int n0 = blockIdx.y * 32;   // over padded 1024
    int k0 = w * 256;
    int lr = lane & 15;
    int lk = (lane >> 4) * 8;

    f32x4 acc[2][2];
#pragma unroll
    for (int i = 0; i < 2; i++)
#pragma unroll
        for (int j = 0; j < 2; j++) acc[i][j] = (f32x4)0.f;

    for (int kk = k0; kk < k0 + 256; kk += 32) {
        bf16x8 a[2], b[2];
#pragma unroll
        for (int i = 0; i < 2; i++)
            a[i] = *(const bf16x8*)(sin + (size_t)(m0 + i * 16 + lr) * RES + kk + lk);
#pragma unroll
        for (int j = 0; j < 2; j++) {
            int row = n0 + j * 16 + lr;
            if (row > NCLS - 1) row = NCLS - 1;  // clamp, result unused
            b[j] = *(const bf16x8*)(wout + (size_t)row * RES + kk + lk);
        }
#pragma unroll
        for (int i = 0; i < 2; i++)
#pragma unroll
            for (int j = 0; j < 2; j++)
                acc[i][j] = __builtin_amdgcn_mfma_f32_16x16x32_bf16(a[i], b[j], acc[i][j], 0, 0, 0);
    }

    int rowbase = (lane >> 4) * 4;
#pragma unroll
    for (int i = 0; i < 2; i++)
#pragma unroll
        for (int j = 0; j < 2; j++)
#pragma unroll
            for (int q = 0; q < 4; q++)
                part[w][i * 16 + rowbase + q][j * 16 + lr] = acc[i][j][q];

    __syncthreads();

    for (int idx = threadIdx.x; idx < 1024; idx += 512) {
        int r = idx >> 5, c = idx & 31;
        float s = 0.f;
#pragma unroll
        for (int ww = 0; ww < 8; ww++) s += part[ww][r][c];
        int cg = n0 + c;
        if (cg < NCLS)
            out[(size_t)(m0 + r) * NCLS + cg] = s + bias[cg];
    }
}

extern "C" void kernel_launch(void* const* d_in, const int* in_sizes, int n_in,
                              void* d_out, int out_size, void* d_ws, size_t ws_size,
                              hipStream_t stream) {
    const float* x_f    = (const float*)d_in[0];  // [128,256,768]
    const float* res_f  = (const float*)d_in[1];  // [2048,2048]
    const float* win_f  = (const float*)d_in[2];  // [2048,768]
    const float* wout_f = (const float*)d_in[3];  // [1000,2048]
    const float* bias   = (const float*)d_in[4];  // [1000]
    float* out = (float*)d_out;

    char* ws = (char*)d_ws;
    size_t off = 0;
    auto alloc = [&](size_t bytes) -> void* {
        void* p = ws + off;
        off += (bytes + 255) & ~(size_t)255;
        return p;
    };
    u16* res_b  = (u16*)alloc((size_t)RES * RES * 2);
    u16* win_b  = (u16*)alloc((size_t)RES * EMBED * 2);
    u16* wout_b = (u16*)alloc((size_t)NCLS * RES * 2);
    u16* x_b    = (u16*)alloc((size_t)BATCH * NFRAMES * EMBED * 2);
    u16* u      = (u16*)alloc((size_t)NFRAMES * BATCH * RES * 2);
    u16* s0     = (u16*)alloc((size_t)BATCH * RES * 2);
    u16* s1     = (u16*)alloc((size_t)BATCH * RES * 2);
    unsigned* flags = (unsigned*)alloc(1024);

    // weight / input conversion to bf16
    cvt_kernel<<<dim3(1024), dim3(256), 0, stream>>>(res_f, res_b, RES * RES / 4);
    cvt_kernel<<<dim3(512), dim3(256), 0, stream>>>(win_f, win_b, RES * EMBED / 4);
    cvt_kernel<<<dim3(512), dim3(256), 0, stream>>>(wout_f, wout_b, NCLS * RES / 4);
    cvt_kernel<<<dim3(2048), dim3(256), 0, stream>>>(x_f, x_b, BATCH * NFRAMES * EMBED / 4);

    // state0 = 0, flags = 0 (ws poisoned 0xAA; re-init every call)
    hipMemsetAsync(s0, 0, (size_t)BATCH * RES * 2, stream);
    hipMemsetAsync(flags, 0, 1024, stream);

    // u[t,b,r] projection GEMM
    proj_kernel<<<dim3(256, 16), dim3(256), 0, stream>>>(x_b, win_b, u);

    // all 256 recurrence steps in one cooperative launch
    void* args[] = { (void*)&res_b, (void*)&u, (void*)&s0, (void*)&s1, (void*)&flags };
    hipLaunchCooperativeKernel((const void*)recur_kernel, dim3(NWG), dim3(512),
                               args, 0, stream);

    // final state is in s0 (t=255 odd -> wrote s0)
    head_kernel<<<dim3(4, 32), dim3(512), 0, stream>>>(s0, wout_b, bias, out);
}

// Round 12
// 1416.689 us; speedup vs baseline: 1.1231x; 1.1231x over previous
//
#include <hip/hip_runtime.h>
#include <stdint.h>
#include <stddef.h>

#define BATCH 128
#define NFRAMES 256
#define EMBED 768
#define RES 2048
#define NCLS 1000
#define NWG 256

typedef __attribute__((ext_vector_type(8))) short bf16x8;
typedef __attribute__((ext_vector_type(4))) float f32x4;
typedef unsigned short u16;

__device__ inline u16 f2bf(float f) {
    union { float f; unsigned u; } v; v.f = f;
    unsigned r = v.u + 0x7FFFu + ((v.u >> 16) & 1u);
    return (u16)(r >> 16);
}
__device__ inline float bf2f(u16 h) {
    union { unsigned u; float f; } v; v.u = ((unsigned)h) << 16;
    return v.f;
}
// tanh(x) = 1 - 2/(e^{2x}+1), via HW exp2 + rcp (4 VALU ops, saturates correctly)
__device__ inline float tanh_fast(float x) {
    float z = __builtin_amdgcn_exp2f(x * 2.885390081777927f);  // e^{2x}
    return 1.f - 2.f * __builtin_amdgcn_rcpf(z + 1.f);
}

// ---------------- fp32 -> bf16 convert, vectorized x4 ----------------
__global__ __launch_bounds__(256) void cvt_kernel(const float* __restrict__ in,
                                                  u16* __restrict__ out, int n4) {
    int i = blockIdx.x * blockDim.x + threadIdx.x;
    int stride = gridDim.x * blockDim.x;
    for (; i < n4; i += stride) {
        float4 v = ((const float4*)in)[i];
        ushort4 o;
        o.x = f2bf(v.x); o.y = f2bf(v.y); o.z = f2bf(v.z); o.w = f2bf(v.w);
        ((ushort4*)out)[i] = o;
    }
}

// ---------------- projection: u[t,b,r] = sum_e x[b,t,e] * W_in[r,e] ----------------
__global__ __launch_bounds__(256) void proj_kernel(const u16* __restrict__ xb,
                                                   const u16* __restrict__ win,
                                                   u16* __restrict__ u) {
    int lane = threadIdx.x & 63;
    int w = threadIdx.x >> 6;
    int wm = w >> 1, wn = w & 1;
    int m0 = blockIdx.x * 128 + wm * 64;
    int n0 = blockIdx.y * 128 + wn * 64;
    int lr = lane & 15;
    int lk = (lane >> 4) * 8;

    f32x4 acc[4][4];
#pragma unroll
    for (int i = 0; i < 4; i++)
#pragma unroll
        for (int j = 0; j < 4; j++) acc[i][j] = (f32x4)0.f;

    for (int kk = 0; kk < EMBED; kk += 32) {
        bf16x8 a[4], b[4];
#pragma unroll
        for (int i = 0; i < 4; i++)
            a[i] = *(const bf16x8*)(xb + (size_t)(m0 + i * 16 + lr) * EMBED + kk + lk);
#pragma unroll
        for (int j = 0; j < 4; j++)
            b[j] = *(const bf16x8*)(win + (size_t)(n0 + j * 16 + lr) * EMBED + kk + lk);
#pragma unroll
        for (int i = 0; i < 4; i++)
#pragma unroll
            for (int j = 0; j < 4; j++)
                acc[i][j] = __builtin_amdgcn_mfma_f32_16x16x32_bf16(a[i], b[j], acc[i][j], 0, 0, 0);
    }

    int rowbase = (lane >> 4) * 4;
#pragma unroll
    for (int i = 0; i < 4; i++) {
#pragma unroll
        for (int j = 0; j < 4; j++) {
#pragma unroll
            for (int q = 0; q < 4; q++) {
                int m = m0 + i * 16 + rowbase + q;   // row index = b*NFRAMES + t
                int n = n0 + j * 16 + lr;            // reservoir index
                int bb = m >> 8, tt = m & 255;
                u[((size_t)tt * BATCH + bb) * RES + n] = f2bf(acc[i][j][q]);
            }
        }
    }
}

// ---------------- persistent recurrence, row-groups + state ring in u ----------------
// Batch rows independent -> 8 row-groups of 32 WGs. WG tile 16 rows x 64 cols,
// 8 waves K-split 8x256, B persistent in VGPRs (128/lane).
// state[t] overwrites slot u[t] (dead after step t). Ring => addresses never
// reused => plain CACHED A-loads are safe with no fences: every line is either
// cold (fresh IF fetch; no XCD ever cached it) or owner-XCD (updated by the
// owner's sc0sc1 write-through). Proj-era cached u lines are cleared by the
// inter-dispatch AQL cache flush/invalidate (verified empirically in R7).
// Sync: per-row-group stamp flags (sc0sc1, monotone), wave-0 poll of 32 flags.
__global__ __launch_bounds__(512, 1) void recur_kernel(const u16* __restrict__ res,
                                                       u16* __restrict__ u,
                                                       const u16* __restrict__ s0,
                                                       unsigned* __restrict__ flags) {
    __shared__ float part[8][16][66];
    const int lane = threadIdx.x & 63;
    const int w = threadIdx.x >> 6;          // K-slice 0..7
    const int rowgrp = (int)(blockIdx.x & 7);
    const int colblk = (int)(blockIdx.x >> 3);
    const int m0 = rowgrp * 16;
    const int n0 = colblk * 64;
    const int lr = lane & 15;
    const int lk = (lane >> 4) * 8;
    const int rb = (lane >> 4) * 4;
    const int kbase = w * 256;
    unsigned* myflag = flags + rowgrp * 32 + colblk;
    const unsigned* pollflag = flags + rowgrp * 32 + (lane & 31);

    // persistent reservoir B-fragments: 4 col-frags x 8 K-subs = 128 VGPR/lane
    bf16x8 bfr[4][8];
#pragma unroll
    for (int jf = 0; jf < 4; jf++)
#pragma unroll
        for (int kk = 0; kk < 8; kk++)
            bfr[jf][kk] = *(const bf16x8*)(res + (size_t)(n0 + jf * 16 + lr) * RES + kbase + kk * 32 + lk);

    // epilogue mapping: thread -> (row 0..15, col pair)
    const int er = threadIdx.x >> 5;          // 0..15
    const int ec = (threadIdx.x & 31) * 2;    // 0..62
    const size_t gidx = (size_t)(m0 + er) * RES + n0 + ec;

    for (int t = 0; t < NFRAMES; t++) {
        const u16* sin = (t == 0) ? s0 : u + (size_t)(t - 1) * BATCH * RES;
        u16* sout = u + (size_t)t * BATCH * RES;
        const u16* abase = sin + (size_t)(m0 + lr) * RES + kbase + lk;

        // u value: own elements of slot t, read (cached) before overwrite
        unsigned uv = *(const unsigned*)(sout + gidx);

        // 8 A-loads (16 rows x 256 K slice) -- CACHED (L1/L2; ring makes it safe)
        bf16x8 a[8];
#pragma unroll
        for (int kk = 0; kk < 8; kk++)
            asm volatile("global_load_dwordx4 %0, %1, off"
                         : "=v"(a[kk]) : "v"(abase + kk * 32));

        f32x4 acc[4];
#pragma unroll
        for (int jf = 0; jf < 4; jf++) acc[jf] = (f32x4)0.f;

        asm volatile("s_waitcnt vmcnt(4)" ::: "memory");
        __builtin_amdgcn_sched_barrier(0);
#pragma unroll
        for (int kk = 0; kk < 4; kk++)
#pragma unroll
            for (int jf = 0; jf < 4; jf++)
                acc[jf] = __builtin_amdgcn_mfma_f32_16x16x32_bf16(a[kk], bfr[jf][kk], acc[jf], 0, 0, 0);
        asm volatile("s_waitcnt vmcnt(0)" ::: "memory");
        __builtin_amdgcn_sched_barrier(0);
#pragma unroll
        for (int kk = 4; kk < 8; kk++)
#pragma unroll
            for (int jf = 0; jf < 4; jf++)
                acc[jf] = __builtin_amdgcn_mfma_f32_16x16x32_bf16(a[kk], bfr[jf][kk], acc[jf], 0, 0, 0);

        // K-partials -> LDS
#pragma unroll
        for (int jf = 0; jf < 4; jf++)
#pragma unroll
            for (int q = 0; q < 4; q++)
                part[w][rb + q][jf * 16 + lr] = acc[jf][q];
        __syncthreads();

        // reduce 8 K-partials + u add + fast tanh + packed write-through store
        float sx = 0.f, sy = 0.f;
#pragma unroll
        for (int ww = 0; ww < 8; ww++) {
            float2 v = *(const float2*)&part[ww][er][ec];
            sx += v.x; sy += v.y;
        }
        float v0 = tanh_fast(sx + bf2f((u16)(uv & 0xFFFF)));
        float v1 = tanh_fast(sy + bf2f((u16)(uv >> 16)));
        unsigned pk = (unsigned)f2bf(v0) | ((unsigned)f2bf(v1) << 16);
        asm volatile("global_store_dword %0, %1, off sc0 sc1"
                     :: "v"(sout + gidx), "v"(pk) : "memory");

        // drain own stores (write-through -> visible at IF + owner L2 updated),
        // then ROW-GROUP barrier: stamp + 64-lane poll over the group's 32 flags.
        asm volatile("s_waitcnt vmcnt(0)" ::: "memory");
        __syncthreads();
        if (t != NFRAMES - 1) {
            unsigned stamp = (unsigned)(t + 1);
            if (w == 0) {
                if (lane == 0)
                    asm volatile("global_store_dword %0, %1, off sc0 sc1"
                                 :: "v"(myflag), "v"(stamp) : "memory");
                unsigned f;
                do {
                    asm volatile("global_load_dword %0, %1, off sc0 sc1\n\ts_waitcnt vmcnt(0)"
                                 : "=v"(f) : "v"(pollflag) : "memory");
                    if (__all((int)(f >= stamp))) break;
                    __builtin_amdgcn_s_sleep(2);
                } while (1);
            }
            __syncthreads();
        }
    }
}

// ---------------- head: logits[b,c] = sum_r s[b,r]*W_out[c,r] + bias[c] ----------------
__global__ __launch_bounds__(512) void head_kernel(const u16* __restrict__ sin,
                                                   const u16* __restrict__ wout,
                                                   const float* __restrict__ bias,
                                                   float* __restrict__ out) {
    __shared__ float part[8][32][33];
    int lane = threadIdx.x & 63;
    int w = threadIdx.x >> 6;
    int m0 = blockIdx.x * 32;
    int n0 = blockIdx.y * 32;   // over padded 1024
    int k0 = w * 256;
    int lr = lane & 15;
    int lk = (lane >> 4) * 8;

    f32x4 acc[2][2];
#pragma unroll
    for (int i = 0; i < 2; i++)
#pragma unroll
        for (int j = 0; j < 2; j++) acc[i][j] = (f32x4)0.f;

    for (int kk = k0; kk < k0 + 256; kk += 32) {
        bf16x8 a[2], b[2];
#pragma unroll
        for (int i = 0; i < 2; i++)
            a[i] = *(const bf16x8*)(sin + (size_t)(m0 + i * 16 + lr) * RES + kk + lk);
#pragma unroll
        for (int j = 0; j < 2; j++) {
            int row = n0 + j * 16 + lr;
            if (row > NCLS - 1) row = NCLS - 1;  // clamp, result unused
            b[j] = *(const bf16x8*)(wout + (size_t)row * RES + kk + lk);
        }
#pragma unroll
        for (int i = 0; i < 2; i++)
#pragma unroll
            for (int j = 0; j < 2; j++)
                acc[i][j] = __builtin_amdgcn_mfma_f32_16x16x32_bf16(a[i], b[j], acc[i][j], 0, 0, 0);
    }

    int rowbase = (lane >> 4) * 4;
#pragma unroll
    for (int i = 0; i < 2; i++)
#pragma unroll
        for (int j = 0; j < 2; j++)
#pragma unroll
            for (int q = 0; q < 4; q++)
                part[w][i * 16 + rowbase + q][j * 16 + lr] = acc[i][j][q];

    __syncthreads();

    for (int idx = threadIdx.x; idx < 1024; idx += 512) {
        int r = idx >> 5, c = idx & 31;
        float s = 0.f;
#pragma unroll
        for (int ww = 0; ww < 8; ww++) s += part[ww][r][c];
        int cg = n0 + c;
        if (cg < NCLS)
            out[(size_t)(m0 + r) * NCLS + cg] = s + bias[cg];
    }
}

extern "C" void kernel_launch(void* const* d_in, const int* in_sizes, int n_in,
                              void* d_out, int out_size, void* d_ws, size_t ws_size,
                              hipStream_t stream) {
    const float* x_f    = (const float*)d_in[0];  // [128,256,768]
    const float* res_f  = (const float*)d_in[1];  // [2048,2048]
    const float* win_f  = (const float*)d_in[2];  // [2048,768]
    const float* wout_f = (const float*)d_in[3];  // [1000,2048]
    const float* bias   = (const float*)d_in[4];  // [1000]
    float* out = (float*)d_out;

    char* ws = (char*)d_ws;
    size_t off = 0;
    auto alloc = [&](size_t bytes) -> void* {
        void* p = ws + off;
        off += (bytes + 255) & ~(size_t)255;
        return p;
    };
    u16* res_b  = (u16*)alloc((size_t)RES * RES * 2);
    u16* win_b  = (u16*)alloc((size_t)RES * EMBED * 2);
    u16* wout_b = (u16*)alloc((size_t)NCLS * RES * 2);
    u16* x_b    = (u16*)alloc((size_t)BATCH * NFRAMES * EMBED * 2);
    u16* u      = (u16*)alloc((size_t)NFRAMES * BATCH * RES * 2);  // u / state ring
    u16* s0     = (u16*)alloc((size_t)BATCH * RES * 2);            // zero initial state
    unsigned* flags = (unsigned*)alloc(1024);

    // weight / input conversion to bf16
    cvt_kernel<<<dim3(1024), dim3(256), 0, stream>>>(res_f, res_b, RES * RES / 4);
    cvt_kernel<<<dim3(512), dim3(256), 0, stream>>>(win_f, win_b, RES * EMBED / 4);
    cvt_kernel<<<dim3(512), dim3(256), 0, stream>>>(wout_f, wout_b, NCLS * RES / 4);
    cvt_kernel<<<dim3(2048), dim3(256), 0, stream>>>(x_f, x_b, BATCH * NFRAMES * EMBED / 4);

    // state0 = 0, flags = 0 (ws poisoned 0xAA; re-init every call)
    hipMemsetAsync(s0, 0, (size_t)BATCH * RES * 2, stream);
    hipMemsetAsync(flags, 0, 1024, stream);

    // u[t,b,r] projection GEMM
    proj_kernel<<<dim3(256, 16), dim3(256), 0, stream>>>(x_b, win_b, u);

    // all 256 recurrence steps in one cooperative launch; state[t] -> slot u[t]
    void* args[] = { (void*)&res_b, (void*)&u, (void*)&s0, (void*)&flags };
    hipLaunchCooperativeKernel((const void*)recur_kernel, dim3(NWG), dim3(512),
                               args, 0, stream);

    // final state lives in slot u[255]
    const u16* sfin = u + (size_t)(NFRAMES - 1) * BATCH * RES;
    head_kernel<<<dim3(4, 32), dim3(512), 0, stream>>>(sfin, wout_b, bias, out);
}

// Round 14
// 1412.165 us; speedup vs baseline: 1.1267x; 1.0032x over previous
//
#include <hip/hip_runtime.h>
#include <stdint.h>
#include <stddef.h>

#define BATCH 128
#define NFRAMES 256
#define EMBED 768
#define RES 2048
#define NCLS 1000

typedef __attribute__((ext_vector_type(8))) short bf16x8;
typedef __attribute__((ext_vector_type(4))) float f32x4;
typedef unsigned short u16;

__device__ inline u16 f2bf(float f) {
    union { float f; unsigned u; } v; v.f = f;
    unsigned r = v.u + 0x7FFFu + ((v.u >> 16) & 1u);
    return (u16)(r >> 16);
}
__device__ inline float bf2f(u16 h) {
    union { unsigned u; float f; } v; v.u = ((unsigned)h) << 16;
    return v.f;
}
// tanh(x) = 1 - 2/(e^{2x}+1), via HW exp2 + rcp (4 VALU ops, saturates correctly)
__device__ inline float tanh_fast(float x) {
    float z = __builtin_amdgcn_exp2f(x * 2.885390081777927f);  // e^{2x}
    return 1.f - 2.f * __builtin_amdgcn_rcpf(z + 1.f);
}

// ---------------- fp32 -> bf16 convert, vectorized x4 ----------------
__global__ __launch_bounds__(256) void cvt_kernel(const float* __restrict__ in,
                                                  u16* __restrict__ out, int n4) {
    int i = blockIdx.x * blockDim.x + threadIdx.x;
    int stride = gridDim.x * blockDim.x;
    for (; i < n4; i += stride) {
        float4 v = ((const float4*)in)[i];
        ushort4 o;
        o.x = f2bf(v.x); o.y = f2bf(v.y); o.z = f2bf(v.z); o.w = f2bf(v.w);
        ((ushort4*)out)[i] = o;
    }
}

// ---------------- projection: u[t,b,r] = sum_e x[b,t,e] * W_in[r,e] ----------------
__global__ __launch_bounds__(256) void proj_kernel(const u16* __restrict__ xb,
                                                   const u16* __restrict__ win,
                                                   u16* __restrict__ u) {
    int lane = threadIdx.x & 63;
    int w = threadIdx.x >> 6;
    int wm = w >> 1, wn = w & 1;
    int m0 = blockIdx.x * 128 + wm * 64;
    int n0 = blockIdx.y * 128 + wn * 64;
    int lr = lane & 15;
    int lk = (lane >> 4) * 8;

    f32x4 acc[4][4];
#pragma unroll
    for (int i = 0; i < 4; i++)
#pragma unroll
        for (int j = 0; j < 4; j++) acc[i][j] = (f32x4)0.f;

    for (int kk = 0; kk < EMBED; kk += 32) {
        bf16x8 a[4], b[4];
#pragma unroll
        for (int i = 0; i < 4; i++)
            a[i] = *(const bf16x8*)(xb + (size_t)(m0 + i * 16 + lr) * EMBED + kk + lk);
#pragma unroll
        for (int j = 0; j < 4; j++)
            b[j] = *(const bf16x8*)(win + (size_t)(n0 + j * 16 + lr) * EMBED + kk + lk);
#pragma unroll
        for (int i = 0; i < 4; i++)
#pragma unroll
            for (int j = 0; j < 4; j++)
                acc[i][j] = __builtin_amdgcn_mfma_f32_16x16x32_bf16(a[i], b[j], acc[i][j], 0, 0, 0);
    }

    int rowbase = (lane >> 4) * 4;
#pragma unroll
    for (int i = 0; i < 4; i++) {
#pragma unroll
        for (int j = 0; j < 4; j++) {
#pragma unroll
            for (int q = 0; q < 4; q++) {
                int m = m0 + i * 16 + rowbase + q;   // row index = b*NFRAMES + t
                int n = n0 + j * 16 + lr;            // reservoir index
                int bb = m >> 8, tt = m & 255;
                u[((size_t)tt * BATCH + bb) * RES + n] = f2bf(acc[i][j][q]);
            }
        }
    }
}

// ---------------- recur A: 512 WGs (2/CU), tile 16x32, 2 streams per CU ----------------
// 8 row-groups x 64 col-blocks. Register-budgeted for 16 waves/CU (VGPR<=128):
// bfr[2][8]=64, A-loads in two 4-reg batches. Ring state in u (cached A-loads
// safe), sc0sc1 write-through stores, per-group stamp flags + 64-lane poll.
__global__ __launch_bounds__(512, 4) void recur512_kernel(const u16* __restrict__ res,
                                                          u16* __restrict__ u,
                                                          const u16* __restrict__ s0,
                                                          unsigned* __restrict__ flags) {
    __shared__ float part[8][16][34];
    const int lane = threadIdx.x & 63;
    const int w = threadIdx.x >> 6;
    const int rowgrp = (int)(blockIdx.x & 7);
    const int colblk = (int)(blockIdx.x >> 3);   // 0..63
    const int m0 = rowgrp * 16;
    const int n0 = colblk * 32;
    const int lr = lane & 15;
    const int lk = (lane >> 4) * 8;
    const int rb = (lane >> 4) * 4;
    const int kbase = w * 256;
    unsigned* myflag = flags + rowgrp * 64 + colblk;
    const unsigned* pollflag = flags + rowgrp * 64 + lane;

    bf16x8 bfr[2][8];
#pragma unroll
    for (int jf = 0; jf < 2; jf++)
#pragma unroll
        for (int kk = 0; kk < 8; kk++)
            bfr[jf][kk] = *(const bf16x8*)(res + (size_t)(n0 + jf * 16 + lr) * RES + kbase + kk * 32 + lk);

    const int er = (threadIdx.x & 255) >> 4;
    const int ec = (threadIdx.x & 15) * 2;
    const size_t gidx = (size_t)(m0 + er) * RES + n0 + ec;
    const bool epi = (threadIdx.x < 256);

    for (int t = 0; t < NFRAMES; t++) {
        const u16* sin = (t == 0) ? s0 : u + (size_t)(t - 1) * BATCH * RES;
        u16* sout = u + (size_t)t * BATCH * RES;
        const u16* abase = sin + (size_t)(m0 + lr) * RES + kbase + lk;

        unsigned uv = 0;
        if (epi) uv = *(const unsigned*)(sout + gidx);

        f32x4 acc0 = (f32x4)0.f, acc1 = (f32x4)0.f;
        bf16x8 a0[4], a1[4];
#pragma unroll
        for (int kk = 0; kk < 4; kk++)
            asm volatile("global_load_dwordx4 %0, %1, off"
                         : "=v"(a0[kk]) : "v"(abase + kk * 32));
#pragma unroll
        for (int kk = 0; kk < 4; kk++)
            asm volatile("global_load_dwordx4 %0, %1, off"
                         : "=v"(a1[kk]) : "v"(abase + 128 + kk * 32));

        asm volatile("s_waitcnt vmcnt(4)" ::: "memory");
        __builtin_amdgcn_sched_barrier(0);
#pragma unroll
        for (int kk = 0; kk < 4; kk++) {
            acc0 = __builtin_amdgcn_mfma_f32_16x16x32_bf16(a0[kk], bfr[0][kk], acc0, 0, 0, 0);
            acc1 = __builtin_amdgcn_mfma_f32_16x16x32_bf16(a0[kk], bfr[1][kk], acc1, 0, 0, 0);
        }
        asm volatile("s_waitcnt vmcnt(0)" ::: "memory");
        __builtin_amdgcn_sched_barrier(0);
#pragma unroll
        for (int kk = 0; kk < 4; kk++) {
            acc0 = __builtin_amdgcn_mfma_f32_16x16x32_bf16(a1[kk], bfr[0][kk + 4], acc0, 0, 0, 0);
            acc1 = __builtin_amdgcn_mfma_f32_16x16x32_bf16(a1[kk], bfr[1][kk + 4], acc1, 0, 0, 0);
        }

#pragma unroll
        for (int q = 0; q < 4; q++) {
            part[w][rb + q][lr]      = acc0[q];
            part[w][rb + q][16 + lr] = acc1[q];
        }
        __syncthreads();

        if (epi) {
            float sx = 0.f, sy = 0.f;
#pragma unroll
            for (int ww = 0; ww < 8; ww++) {
                float2 v = *(const float2*)&part[ww][er][ec];
                sx += v.x; sy += v.y;
            }
            float v0 = tanh_fast(sx + bf2f((u16)(uv & 0xFFFF)));
            float v1 = tanh_fast(sy + bf2f((u16)(uv >> 16)));
            unsigned pk = (unsigned)f2bf(v0) | ((unsigned)f2bf(v1) << 16);
            asm volatile("global_store_dword %0, %1, off sc0 sc1"
                         :: "v"(sout + gidx), "v"(pk) : "memory");
        }

        asm volatile("s_waitcnt vmcnt(0)" ::: "memory");
        __syncthreads();
        if (t != NFRAMES - 1) {
            unsigned stamp = (unsigned)(t + 1);
            if (w == 0) {
                if (lane == 0)
                    asm volatile("global_store_dword %0, %1, off sc0 sc1"
                                 :: "v"(myflag), "v"(stamp) : "memory");
                unsigned f;
                do {
                    asm volatile("global_load_dword %0, %1, off sc0 sc1\n\ts_waitcnt vmcnt(0)"
                                 : "=v"(f) : "v"(pollflag) : "memory");
                    if (__all((int)(f >= stamp))) break;
                    __builtin_amdgcn_s_sleep(2);
                } while (1);
            }
            __syncthreads();
        }
    }
}

// ---------------- recur B (fallback): exact R12 kernel, 256 WGs, tile 16x64 ----------------
__global__ __launch_bounds__(512, 1) void recur256_kernel(const u16* __restrict__ res,
                                                          u16* __restrict__ u,
                                                          const u16* __restrict__ s0,
                                                          unsigned* __restrict__ flags) {
    __shared__ float part[8][16][66];
    const int lane = threadIdx.x & 63;
    const int w = threadIdx.x >> 6;
    const int rowgrp = (int)(blockIdx.x & 7);
    const int colblk = (int)(blockIdx.x >> 3);
    const int m0 = rowgrp * 16;
    const int n0 = colblk * 64;
    const int lr = lane & 15;
    const int lk = (lane >> 4) * 8;
    const int rb = (lane >> 4) * 4;
    const int kbase = w * 256;
    unsigned* myflag = flags + rowgrp * 32 + colblk;
    const unsigned* pollflag = flags + rowgrp * 32 + (lane & 31);

    bf16x8 bfr[4][8];
#pragma unroll
    for (int jf = 0; jf < 4; jf++)
#pragma unroll
        for (int kk = 0; kk < 8; kk++)
            bfr[jf][kk] = *(const bf16x8*)(res + (size_t)(n0 + jf * 16 + lr) * RES + kbase + kk * 32 + lk);

    const int er = threadIdx.x >> 5;
    const int ec = (threadIdx.x & 31) * 2;
    const size_t gidx = (size_t)(m0 + er) * RES + n0 + ec;

    for (int t = 0; t < NFRAMES; t++) {
        const u16* sin = (t == 0) ? s0 : u + (size_t)(t - 1) * BATCH * RES;
        u16* sout = u + (size_t)t * BATCH * RES;
        const u16* abase = sin + (size_t)(m0 + lr) * RES + kbase + lk;

        unsigned uv = *(const unsigned*)(sout + gidx);

        bf16x8 a[8];
#pragma unroll
        for (int kk = 0; kk < 8; kk++)
            asm volatile("global_load_dwordx4 %0, %1, off"
                         : "=v"(a[kk]) : "v"(abase + kk * 32));

        f32x4 acc[4];
#pragma unroll
        for (int jf = 0; jf < 4; jf++) acc[jf] = (f32x4)0.f;

        asm volatile("s_waitcnt vmcnt(4)" ::: "memory");
        __builtin_amdgcn_sched_barrier(0);
#pragma unroll
        for (int kk = 0; kk < 4; kk++)
#pragma unroll
            for (int jf = 0; jf < 4; jf++)
                acc[jf] = __builtin_amdgcn_mfma_f32_16x16x32_bf16(a[kk], bfr[jf][kk], acc[jf], 0, 0, 0);
        asm volatile("s_waitcnt vmcnt(0)" ::: "memory");
        __builtin_amdgcn_sched_barrier(0);
#pragma unroll
        for (int kk = 4; kk < 8; kk++)
#pragma unroll
            for (int jf = 0; jf < 4; jf++)
                acc[jf] = __builtin_amdgcn_mfma_f32_16x16x32_bf16(a[kk], bfr[jf][kk], acc[jf], 0, 0, 0);

#pragma unroll
        for (int jf = 0; jf < 4; jf++)
#pragma unroll
            for (int q = 0; q < 4; q++)
                part[w][rb + q][jf * 16 + lr] = acc[jf][q];
        __syncthreads();

        float sx = 0.f, sy = 0.f;
#pragma unroll
        for (int ww = 0; ww < 8; ww++) {
            float2 v = *(const float2*)&part[ww][er][ec];
            sx += v.x; sy += v.y;
        }
        float v0 = tanh_fast(sx + bf2f((u16)(uv & 0xFFFF)));
        float v1 = tanh_fast(sy + bf2f((u16)(uv >> 16)));
        unsigned pk = (unsigned)f2bf(v0) | ((unsigned)f2bf(v1) << 16);
        asm volatile("global_store_dword %0, %1, off sc0 sc1"
                     :: "v"(sout + gidx), "v"(pk) : "memory");

        asm volatile("s_waitcnt vmcnt(0)" ::: "memory");
        __syncthreads();
        if (t != NFRAMES - 1) {
            unsigned stamp = (unsigned)(t + 1);
            if (w == 0) {
                if (lane == 0)
                    asm volatile("global_store_dword %0, %1, off sc0 sc1"
                                 :: "v"(myflag), "v"(stamp) : "memory");
                unsigned f;
                do {
                    asm volatile("global_load_dword %0, %1, off sc0 sc1\n\ts_waitcnt vmcnt(0)"
                                 : "=v"(f) : "v"(pollflag) : "memory");
                    if (__all((int)(f >= stamp))) break;
                    __builtin_amdgcn_s_sleep(2);
                } while (1);
            }
            __syncthreads();
        }
    }
}

// ---------------- head: logits[b,c] = sum_r s[b,r]*W_out[c,r] + bias[c] ----------------
__global__ __launch_bounds__(512) void head_kernel(const u16* __restrict__ sin,
                                                   const u16* __restrict__ wout,
                                                   const float* __restrict__ bias,
                                                   float* __restrict__ out) {
    __shared__ float part[8][32][33];
    int lane = threadIdx.x & 63;
    int w = threadIdx.x >> 6;
    int m0 = blockIdx.x * 32;
    int n0 = blockIdx.y * 32;   // over padded 1024
    int k0 = w * 256;
    int lr = lane & 15;
    int lk = (lane >> 4) * 8;

    f32x4 acc[2][2];
#pragma unroll
    for (int i = 0; i < 2; i++)
#pragma unroll
        for (int j = 0; j < 2; j++) acc[i][j] = (f32x4)0.f;

    for (int kk = k0; kk < k0 + 256; kk += 32) {
        bf16x8 a[2], b[2];
#pragma unroll
        for (int i = 0; i < 2; i++)
            a[i] = *(const bf16x8*)(sin + (size_t)(m0 + i * 16 + lr) * RES + kk + lk);
#pragma unroll
        for (int j = 0; j < 2; j++) {
            int row = n0 + j * 16 + lr;
            if (row > NCLS - 1) row = NCLS - 1;  // clamp, result unused
            b[j] = *(const bf16x8*)(wout + (size_t)row * RES + kk + lk);
        }
#pragma unroll
        for (int i = 0; i < 2; i++)
#pragma unroll
            for (int j = 0; j < 2; j++)
                acc[i][j] = __builtin_amdgcn_mfma_f32_16x16x32_bf16(a[i], b[j], acc[i][j], 0, 0, 0);
    }

    int rowbase = (lane >> 4) * 4;
#pragma unroll
    for (int i = 0; i < 2; i++)
#pragma unroll
        for (int j = 0; j < 2; j++)
#pragma unroll
            for (int q = 0; q < 4; q++)
                part[w][i * 16 + rowbase + q][j * 16 + lr] = acc[i][j][q];

    __syncthreads();

    for (int idx = threadIdx.x; idx < 1024; idx += 512) {
        int r = idx >> 5, c = idx & 31;
        float s = 0.f;
#pragma unroll
        for (int ww = 0; ww < 8; ww++) s += part[ww][r][c];
        int cg = n0 + c;
        if (cg < NCLS)
            out[(size_t)(m0 + r) * NCLS + cg] = s + bias[cg];
    }
}

extern "C" void kernel_launch(void* const* d_in, const int* in_sizes, int n_in,
                              void* d_out, int out_size, void* d_ws, size_t ws_size,
                              hipStream_t stream) {
    const float* x_f    = (const float*)d_in[0];  // [128,256,768]
    const float* res_f  = (const float*)d_in[1];  // [2048,2048]
    const float* win_f  = (const float*)d_in[2];  // [2048,768]
    const float* wout_f = (const float*)d_in[3];  // [1000,2048]
    const float* bias   = (const float*)d_in[4];  // [1000]
    float* out = (float*)d_out;

    char* ws = (char*)d_ws;
    size_t off = 0;
    auto alloc = [&](size_t bytes) -> void* {
        void* p = ws + off;
        off += (bytes + 255) & ~(size_t)255;
        return p;
    };
    u16* res_b  = (u16*)alloc((size_t)RES * RES * 2);
    u16* win_b  = (u16*)alloc((size_t)RES * EMBED * 2);
    u16* wout_b = (u16*)alloc((size_t)NCLS * RES * 2);
    u16* x_b    = (u16*)alloc((size_t)BATCH * NFRAMES * EMBED * 2);
    u16* u      = (u16*)alloc((size_t)NFRAMES * BATCH * RES * 2);  // u / state ring
    u16* s0     = (u16*)alloc((size_t)BATCH * RES * 2);            // zero initial state
    unsigned* flags = (unsigned*)alloc(2048);

    // weight / input conversion to bf16
    cvt_kernel<<<dim3(1024), dim3(256), 0, stream>>>(res_f, res_b, RES * RES / 4);
    cvt_kernel<<<dim3(512), dim3(256), 0, stream>>>(win_f, win_b, RES * EMBED / 4);
    cvt_kernel<<<dim3(512), dim3(256), 0, stream>>>(wout_f, wout_b, NCLS * RES / 4);
    cvt_kernel<<<dim3(2048), dim3(256), 0, stream>>>(x_f, x_b, BATCH * NFRAMES * EMBED / 4);

    // state0 = 0, flags = 0 (ws poisoned 0xAA; re-init every call)
    hipMemsetAsync(s0, 0, (size_t)BATCH * RES * 2, stream);
    hipMemsetAsync(flags, 0, 2048, stream);

    // u[t,b,r] projection GEMM
    proj_kernel<<<dim3(256, 16), dim3(256), 0, stream>>>(x_b, win_b, u);

    // recurrence: prefer 2-streams-per-CU (512 WGs) IF it can co-reside;
    // host-side occupancy query is graph-capture safe and deterministic.
    int blocksPerCU = 0;
    hipOccupancyMaxActiveBlocksPerMultiprocessor(&blocksPerCU,
                                                 (const void*)recur512_kernel, 512, 0);
    void* args[] = { (void*)&res_b, (void*)&u, (void*)&s0, (void*)&flags };
    if (blocksPerCU >= 2) {
        hipLaunchCooperativeKernel((const void*)recur512_kernel, dim3(512), dim3(512),
                                   args, 0, stream);
    } else {
        hipLaunchCooperativeKernel((const void*)recur256_kernel, dim3(256), dim3(512),
                                   args, 0, stream);
    }

    // final state lives in slot u[255]
    const u16* sfin = u + (size_t)(NFRAMES - 1) * BATCH * RES;
    head_kernel<<<dim3(4, 32), dim3(512), 0, stream>>>(sfin, wout_b, bias, out);
}

// Round 15
// 1405.217 us; speedup vs baseline: 1.1323x; 1.0049x over previous
//
#include <hip/hip_runtime.h>
#include <stdint.h>
#include <stddef.h>

#define BATCH 128
#define NFRAMES 256
#define EMBED 768
#define RES 2048
#define NCLS 1000
#define NWG 256

typedef __attribute__((ext_vector_type(8))) short bf16x8;
typedef __attribute__((ext_vector_type(4))) float f32x4;
typedef unsigned short u16;

__device__ inline u16 f2bf(float f) {
    union { float f; unsigned u; } v; v.f = f;
    unsigned r = v.u + 0x7FFFu + ((v.u >> 16) & 1u);
    return (u16)(r >> 16);
}
__device__ inline float bf2f(u16 h) {
    union { unsigned u; float f; } v; v.u = ((unsigned)h) << 16;
    return v.f;
}
// tanh(x) = 1 - 2/(e^{2x}+1), via HW exp2 + rcp (4 VALU ops, saturates correctly)
__device__ inline float tanh_fast(float x) {
    float z = __builtin_amdgcn_exp2f(x * 2.885390081777927f);  // e^{2x}
    return 1.f - 2.f * __builtin_amdgcn_rcpf(z + 1.f);
}

// ---------------- fp32 -> bf16 convert, vectorized x4 ----------------
__global__ __launch_bounds__(256) void cvt_kernel(const float* __restrict__ in,
                                                  u16* __restrict__ out, int n4) {
    int i = blockIdx.x * blockDim.x + threadIdx.x;
    int stride = gridDim.x * blockDim.x;
    for (; i < n4; i += stride) {
        float4 v = ((const float4*)in)[i];
        ushort4 o;
        o.x = f2bf(v.x); o.y = f2bf(v.y); o.z = f2bf(v.z); o.w = f2bf(v.w);
        ((ushort4*)out)[i] = o;
    }
}

// ---------------- projection: u[t,b,r] = sum_e x[b,t,e] * W_in[r,e] ----------------
__global__ __launch_bounds__(256) void proj_kernel(const u16* __restrict__ xb,
                                                   const u16* __restrict__ win,
                                                   u16* __restrict__ u) {
    int lane = threadIdx.x & 63;
    int w = threadIdx.x >> 6;
    int wm = w >> 1, wn = w & 1;
    int m0 = blockIdx.x * 128 + wm * 64;
    int n0 = blockIdx.y * 128 + wn * 64;
    int lr = lane & 15;
    int lk = (lane >> 4) * 8;

    f32x4 acc[4][4];
#pragma unroll
    for (int i = 0; i < 4; i++)
#pragma unroll
        for (int j = 0; j < 4; j++) acc[i][j] = (f32x4)0.f;

    for (int kk = 0; kk < EMBED; kk += 32) {
        bf16x8 a[4], b[4];
#pragma unroll
        for (int i = 0; i < 4; i++)
            a[i] = *(const bf16x8*)(xb + (size_t)(m0 + i * 16 + lr) * EMBED + kk + lk);
#pragma unroll
        for (int j = 0; j < 4; j++)
            b[j] = *(const bf16x8*)(win + (size_t)(n0 + j * 16 + lr) * EMBED + kk + lk);
#pragma unroll
        for (int i = 0; i < 4; i++)
#pragma unroll
            for (int j = 0; j < 4; j++)
                acc[i][j] = __builtin_amdgcn_mfma_f32_16x16x32_bf16(a[i], b[j], acc[i][j], 0, 0, 0);
    }

    int rowbase = (lane >> 4) * 4;
#pragma unroll
    for (int i = 0; i < 4; i++) {
#pragma unroll
        for (int j = 0; j < 4; j++) {
#pragma unroll
            for (int q = 0; q < 4; q++) {
                int m = m0 + i * 16 + rowbase + q;   // row index = b*NFRAMES + t
                int n = n0 + j * 16 + lr;            // reservoir index
                int bb = m >> 8, tt = m & 255;
                u[((size_t)tt * BATCH + bb) * RES + n] = f2bf(acc[i][j][q]);
            }
        }
    }
}

// ---------------- persistent recurrence (R12 + TRUE B-fragment persistence) ----------------
// 8 row-groups x 32 col-blocks = 256 WGs, tile 16 rows x 64 cols, 8 waves K-split.
// KEY FIX: bfr loaded via asm volatile -> compiler CANNOT rematerialize; the 128
// VGPRs of reservoir fragments stay resident across all 256 steps (R12's plain
// loads were re-issued every step = 256 KB/WG/step hidden ingest).
// state[t] lives in dead slot u[t] (ring -> cached A-loads safe, no fences).
// Stores write-through sc0sc1; per-group stamp flags + 64-lane poll.
__global__ __launch_bounds__(512, 1) void recur_kernel(const u16* __restrict__ res,
                                                       u16* __restrict__ u,
                                                       const u16* __restrict__ s0,
                                                       unsigned* __restrict__ flags) {
    __shared__ float part[8][16][66];
    const int lane = threadIdx.x & 63;
    const int w = threadIdx.x >> 6;
    const int rowgrp = (int)(blockIdx.x & 7);
    const int colblk = (int)(blockIdx.x >> 3);
    const int m0 = rowgrp * 16;
    const int n0 = colblk * 64;
    const int lr = lane & 15;
    const int lk = (lane >> 4) * 8;
    const int rb = (lane >> 4) * 4;
    const int kbase = w * 256;
    unsigned* myflag = flags + rowgrp * 32 + colblk;
    const unsigned* pollflag = flags + rowgrp * 32 + (lane & 31);

    // reservoir B-fragments, FORCED persistent via asm loads (128 VGPR/lane)
    bf16x8 bfr[4][8];
#pragma unroll
    for (int jf = 0; jf < 4; jf++)
#pragma unroll
        for (int kk = 0; kk < 8; kk++) {
            const u16* bp = res + (size_t)(n0 + jf * 16 + lr) * RES + kbase + kk * 32 + lk;
            asm volatile("global_load_dwordx4 %0, %1, off"
                         : "=v"(bfr[jf][kk]) : "v"(bp));
        }
    asm volatile("s_waitcnt vmcnt(0)" ::: "memory");

    const int er = threadIdx.x >> 5;
    const int ec = (threadIdx.x & 31) * 2;
    const size_t gidx = (size_t)(m0 + er) * RES + n0 + ec;

    for (int t = 0; t < NFRAMES; t++) {
        const u16* sin = (t == 0) ? s0 : u + (size_t)(t - 1) * BATCH * RES;
        u16* sout = u + (size_t)t * BATCH * RES;
        const u16* abase = sin + (size_t)(m0 + lr) * RES + kbase + lk;

        // u value: own elements of slot t, read (cached) before overwrite
        unsigned uv = *(const unsigned*)(sout + gidx);

        // 8 A-loads (16 rows x 256 K slice), cached (ring makes it safe)
        bf16x8 a[8];
#pragma unroll
        for (int kk = 0; kk < 8; kk++)
            asm volatile("global_load_dwordx4 %0, %1, off"
                         : "=v"(a[kk]) : "v"(abase + kk * 32));

        f32x4 acc[4];
#pragma unroll
        for (int jf = 0; jf < 4; jf++) acc[jf] = (f32x4)0.f;

        asm volatile("s_waitcnt vmcnt(4)" ::: "memory");
        __builtin_amdgcn_sched_barrier(0);
#pragma unroll
        for (int kk = 0; kk < 4; kk++)
#pragma unroll
            for (int jf = 0; jf < 4; jf++)
                acc[jf] = __builtin_amdgcn_mfma_f32_16x16x32_bf16(a[kk], bfr[jf][kk], acc[jf], 0, 0, 0);
        asm volatile("s_waitcnt vmcnt(0)" ::: "memory");
        __builtin_amdgcn_sched_barrier(0);
#pragma unroll
        for (int kk = 4; kk < 8; kk++)
#pragma unroll
            for (int jf = 0; jf < 4; jf++)
                acc[jf] = __builtin_amdgcn_mfma_f32_16x16x32_bf16(a[kk], bfr[jf][kk], acc[jf], 0, 0, 0);

        // K-partials -> LDS
#pragma unroll
        for (int jf = 0; jf < 4; jf++)
#pragma unroll
            for (int q = 0; q < 4; q++)
                part[w][rb + q][jf * 16 + lr] = acc[jf][q];
        __syncthreads();

        // reduce 8 K-partials + u add + fast tanh + packed write-through store
        float sx = 0.f, sy = 0.f;
#pragma unroll
        for (int ww = 0; ww < 8; ww++) {
            float2 v = *(const float2*)&part[ww][er][ec];
            sx += v.x; sy += v.y;
        }
        float v0 = tanh_fast(sx + bf2f((u16)(uv & 0xFFFF)));
        float v1 = tanh_fast(sy + bf2f((u16)(uv >> 16)));
        unsigned pk = (unsigned)f2bf(v0) | ((unsigned)f2bf(v1) << 16);
        asm volatile("global_store_dword %0, %1, off sc0 sc1"
                     :: "v"(sout + gidx), "v"(pk) : "memory");

        // drain own stores, then ROW-GROUP barrier: stamp + 64-lane poll (32 flags)
        asm volatile("s_waitcnt vmcnt(0)" ::: "memory");
        __syncthreads();
        if (t != NFRAMES - 1) {
            unsigned stamp = (unsigned)(t + 1);
            if (w == 0) {
                if (lane == 0)
                    asm volatile("global_store_dword %0, %1, off sc0 sc1"
                                 :: "v"(myflag), "v"(stamp) : "memory");
                unsigned f;
                do {
                    asm volatile("global_load_dword %0, %1, off sc0 sc1\n\ts_waitcnt vmcnt(0)"
                                 : "=v"(f) : "v"(pollflag) : "memory");
                    if (__all((int)(f >= stamp))) break;
                    __builtin_amdgcn_s_sleep(2);
                } while (1);
            }
            __syncthreads();
        }
    }
}

// ---------------- head: logits[b,c] = sum_r s[b,r]*W_out[c,r] + bias[c] ----------------
__global__ __launch_bounds__(512) void head_kernel(const u16* __restrict__ sin,
                                                   const u16* __restrict__ wout,
                                                   const float* __restrict__ bias,
                                                   float* __restrict__ out) {
    __shared__ float part[8][32][33];
    int lane = threadIdx.x & 63;
    int w = threadIdx.x >> 6;
    int m0 = blockIdx.x * 32;
    int n0 = blockIdx.y * 32;   // over padded 1024
    int k0 = w * 256;
    int lr = lane & 15;
    int lk = (lane >> 4) * 8;

    f32x4 acc[2][2];
#pragma unroll
    for (int i = 0; i < 2; i++)
#pragma unroll
        for (int j = 0; j < 2; j++) acc[i][j] = (f32x4)0.f;

    for (int kk = k0; kk < k0 + 256; kk += 32) {
        bf16x8 a[2], b[2];
#pragma unroll
        for (int i = 0; i < 2; i++)
            a[i] = *(const bf16x8*)(sin + (size_t)(m0 + i * 16 + lr) * RES + kk + lk);
#pragma unroll
        for (int j = 0; j < 2; j++) {
            int row = n0 + j * 16 + lr;
            if (row > NCLS - 1) row = NCLS - 1;  // clamp, result unused
            b[j] = *(const bf16x8*)(wout + (size_t)row * RES + kk + lk);
        }
#pragma unroll
        for (int i = 0; i < 2; i++)
#pragma unroll
            for (int j = 0; j < 2; j++)
                acc[i][j] = __builtin_amdgcn_mfma_f32_16x16x32_bf16(a[i], b[j], acc[i][j], 0, 0, 0);
    }

    int rowbase = (lane >> 4) * 4;
#pragma unroll
    for (int i = 0; i < 2; i++)
#pragma unroll
        for (int j = 0; j < 2; j++)
#pragma unroll
            for (int q = 0; q < 4; q++)
                part[w][i * 16 + rowbase + q][j * 16 + lr] = acc[i][j][q];

    __syncthreads();

    for (int idx = threadIdx.x; idx < 1024; idx += 512) {
        int r = idx >> 5, c = idx & 31;
        float s = 0.f;
#pragma unroll
        for (int ww = 0; ww < 8; ww++) s += part[ww][r][c];
        int cg = n0 + c;
        if (cg < NCLS)
            out[(size_t)(m0 + r) * NCLS + cg] = s + bias[cg];
    }
}

extern "C" void kernel_launch(void* const* d_in, const int* in_sizes, int n_in,
                              void* d_out, int out_size, void* d_ws, size_t ws_size,
                              hipStream_t stream) {
    const float* x_f    = (const float*)d_in[0];  // [128,256,768]
    const float* res_f  = (const float*)d_in[1];  // [2048,2048]
    const float* win_f  = (const float*)d_in[2];  // [2048,768]
    const float* wout_f = (const float*)d_in[3];  // [1000,2048]
    const float* bias   = (const float*)d_in[4];  // [1000]
    float* out = (float*)d_out;

    char* ws = (char*)d_ws;
    size_t off = 0;
    auto alloc = [&](size_t bytes) -> void* {
        void* p = ws + off;
        off += (bytes + 255) & ~(size_t)255;
        return p;
    };
    u16* res_b  = (u16*)alloc((size_t)RES * RES * 2);
    u16* win_b  = (u16*)alloc((size_t)RES * EMBED * 2);
    u16* wout_b = (u16*)alloc((size_t)NCLS * RES * 2);
    u16* x_b    = (u16*)alloc((size_t)BATCH * NFRAMES * EMBED * 2);
    u16* u      = (u16*)alloc((size_t)NFRAMES * BATCH * RES * 2);  // u / state ring
    u16* s0     = (u16*)alloc((size_t)BATCH * RES * 2);            // zero initial state
    unsigned* flags = (unsigned*)alloc(1024);

    // weight / input conversion to bf16
    cvt_kernel<<<dim3(1024), dim3(256), 0, stream>>>(res_f, res_b, RES * RES / 4);
    cvt_kernel<<<dim3(512), dim3(256), 0, stream>>>(win_f, win_b, RES * EMBED / 4);
    cvt_kernel<<<dim3(512), dim3(256), 0, stream>>>(wout_f, wout_b, NCLS * RES / 4);
    cvt_kernel<<<dim3(2048), dim3(256), 0, stream>>>(x_f, x_b, BATCH * NFRAMES * EMBED / 4);

    // state0 = 0, flags = 0 (ws poisoned 0xAA; re-init every call)
    hipMemsetAsync(s0, 0, (size_t)BATCH * RES * 2, stream);
    hipMemsetAsync(flags, 0, 1024, stream);

    // u[t,b,r] projection GEMM
    proj_kernel<<<dim3(256, 16), dim3(256), 0, stream>>>(x_b, win_b, u);

    // all 256 recurrence steps in one cooperative launch; state[t] -> slot u[t]
    void* args[] = { (void*)&res_b, (void*)&u, (void*)&s0, (void*)&flags };
    hipLaunchCooperativeKernel((const void*)recur_kernel, dim3(NWG), dim3(512),
                               args, 0, stream);

    // final state lives in slot u[255]
    const u16* sfin = u + (size_t)(NFRAMES - 1) * BATCH * RES;
    head_kernel<<<dim3(4, 32), dim3(512), 0, stream>>>(sfin, wout_b, bias, out);
}